// Round 1
// baseline (353.956 us; speedup 1.0000x reference)
//
#include <hip/hip_runtime.h>

constexpr int B  = 2;
constexpr int NH = 8;
constexpr int L  = 512;
constexpr int D  = 64;
constexpr float INV_TEMP = 0.125f;   // 1/sqrt(D) = 1/8

// ---------------------------------------------------------------------------
// K1: S1[b,h,i,j] = (q[b,h,i,:]/8) . k[b,h,j,:]   -> written into attn region
// grid (B*NH, L/64, L/64), block 256. fp32 LDS-tiled GEMM, 4x4 per thread.
// ---------------------------------------------------------------------------
__global__ __launch_bounds__(256) void k1_qk(const float* __restrict__ q,
                                             const float* __restrict__ k,
                                             float* __restrict__ s1) {
  const int bh = blockIdx.x, it = blockIdx.y, jt = blockIdx.z;
  __shared__ float As[64][65];   // +1 pad: scalar reads land 2-way max (free)
  __shared__ float Bs[64][65];
  const int t = threadIdx.x;
  const float* qb = q + ((size_t)bh * L + it * 64) * D;
  const float* kb = k + ((size_t)bh * L + jt * 64) * D;
#pragma unroll
  for (int n = 0; n < 4; ++n) {
    int idx = t + (n << 8);
    int r = idx >> 4, c = (idx & 15) << 2;
    float4 a = *(const float4*)(qb + r * D + c);
    As[r][c] = a.x * INV_TEMP; As[r][c + 1] = a.y * INV_TEMP;
    As[r][c + 2] = a.z * INV_TEMP; As[r][c + 3] = a.w * INV_TEMP;
    float4 bb = *(const float4*)(kb + r * D + c);
    Bs[r][c] = bb.x; Bs[r][c + 1] = bb.y; Bs[r][c + 2] = bb.z; Bs[r][c + 3] = bb.w;
  }
  __syncthreads();
  const int ti = (t >> 4) << 2, tj = (t & 15) << 2;
  float acc[4][4] = {};
#pragma unroll 8
  for (int kk = 0; kk < 64; ++kk) {
    float a0 = As[ti][kk], a1 = As[ti + 1][kk], a2 = As[ti + 2][kk], a3 = As[ti + 3][kk];
    float b0 = Bs[tj][kk], b1 = Bs[tj + 1][kk], b2 = Bs[tj + 2][kk], b3 = Bs[tj + 3][kk];
    acc[0][0] += a0 * b0; acc[0][1] += a0 * b1; acc[0][2] += a0 * b2; acc[0][3] += a0 * b3;
    acc[1][0] += a1 * b0; acc[1][1] += a1 * b1; acc[1][2] += a1 * b2; acc[1][3] += a1 * b3;
    acc[2][0] += a2 * b0; acc[2][1] += a2 * b1; acc[2][2] += a2 * b2; acc[2][3] += a2 * b3;
    acc[3][0] += a3 * b0; acc[3][1] += a3 * b1; acc[3][2] += a3 * b2; acc[3][3] += a3 * b3;
  }
  float* srow = s1 + ((size_t)bh * L + it * 64) * L + jt * 64;
#pragma unroll
  for (int m = 0; m < 4; ++m)
    *(float4*)(srow + (size_t)(it * 0 + ti + m) * L + tj) =
        make_float4(acc[m][0], acc[m][1], acc[m][2], acc[m][3]);
}

// ---------------------------------------------------------------------------
// K2: per (b,i): score[h,j] = S1[b,h,i,j] + (q/8).adj_k[b,i,j,:]; mask;
//     softmax over j; write attn in place. grid (B*L), block 256.
// ---------------------------------------------------------------------------
__global__ __launch_bounds__(256) void k2_rel_softmax(const float* __restrict__ q,
                                                      const float* __restrict__ adj_k,
                                                      const int* __restrict__ mask,
                                                      float* __restrict__ attn) {
  const int b = blockIdx.x >> 9, i = blockIdx.x & (L - 1);
  __shared__ float qs[NH][D];    // 2 KB
  __shared__ float sc[NH][L];    // 16 KB
  __shared__ float ak[64][65];   // 16.6 KB, padded
  const int t = threadIdx.x;
  for (int n = t; n < NH * D; n += 256) {
    int h = n >> 6, d = n & 63;
    qs[h][d] = q[(((size_t)b * NH + h) * L + i) * D + d] * INV_TEMP;
  }
  const float* akb = adj_k + ((size_t)b * L + i) * (size_t)L * D;
  const int j = t & 63, hq = t >> 6;         // this thread: heads hq and hq+4
  for (int jt = 0; jt < L; jt += 64) {
    __syncthreads();  // protects qs (1st iter) and ak reuse (later iters)
#pragma unroll
    for (int n = 0; n < 4; ++n) {
      int idx = t + (n << 8);
      int r = idx >> 4, c = (idx & 15) << 2;
      float4 a = *(const float4*)(akb + (size_t)(jt + r) * D + c);
      ak[r][c] = a.x; ak[r][c + 1] = a.y; ak[r][c + 2] = a.z; ak[r][c + 3] = a.w;
    }
    __syncthreads();
    float acc0 = 0.f, acc1 = 0.f;
#pragma unroll
    for (int d = 0; d < 64; d += 4) {
      float4 q0 = *(const float4*)&qs[hq][d];
      float4 q1 = *(const float4*)&qs[hq + 4][d];
      float k0 = ak[j][d], k1 = ak[j][d + 1], k2 = ak[j][d + 2], k3 = ak[j][d + 3];
      acc0 += q0.x * k0 + q0.y * k1 + q0.z * k2 + q0.w * k3;
      acc1 += q1.x * k0 + q1.y * k1 + q1.z * k2 + q1.w * k3;
    }
    sc[hq][jt + j] = acc0;
    sc[hq + 4][jt + j] = acc1;
  }
  __syncthreads();
  // softmax: one 32-lane group per head row
  const int h = t >> 5, l = t & 31;
  float* s1row = attn + (((size_t)b * NH + h) * L + i) * L;
  const int* mrow = mask + b * L;
  float vals[16];
  float mx = -3.4e38f;
#pragma unroll
  for (int m = 0; m < 16; ++m) {
    int jj = l + (m << 5);
    float vsc = sc[h][jj] + s1row[jj];
    vsc = (mrow[jj] == 0) ? -10000.0f : vsc;
    vals[m] = vsc;
    mx = fmaxf(mx, vsc);
  }
#pragma unroll
  for (int off = 16; off > 0; off >>= 1) mx = fmaxf(mx, __shfl_xor(mx, off, 32));
  float sum = 0.f;
#pragma unroll
  for (int m = 0; m < 16; ++m) { vals[m] = __expf(vals[m] - mx); sum += vals[m]; }
#pragma unroll
  for (int off = 16; off > 0; off >>= 1) sum += __shfl_xor(sum, off, 32);
  const float inv = 1.0f / sum;
#pragma unroll
  for (int m = 0; m < 16; ++m) s1row[l + (m << 5)] = vals[m] * inv;
}

// ---------------------------------------------------------------------------
// K3a: out[b,h,i,d] = sum_j attn[b,h,i,j] * v[b,h,j,d]
// grid (B*NH, L/64), block 256. fp32 LDS-tiled GEMM, 4x4 per thread.
// ---------------------------------------------------------------------------
__global__ __launch_bounds__(256) void k3a_av(const float* __restrict__ attn,
                                              const float* __restrict__ v,
                                              float* __restrict__ out) {
  const int bh = blockIdx.x, it = blockIdx.y;
  __shared__ float At[64][65];
  __shared__ float Vt[64][65];
  const int t = threadIdx.x;
  const float* arow = attn + ((size_t)bh * L + it * 64) * L;
  const float* vb = v + (size_t)bh * L * D;
  const int ti = (t >> 4) << 2, td = (t & 15) << 2;
  float acc[4][4] = {};
  for (int jt = 0; jt < L; jt += 64) {
    __syncthreads();
#pragma unroll
    for (int n = 0; n < 4; ++n) {
      int idx = t + (n << 8);
      int r = idx >> 4, c = (idx & 15) << 2;
      float4 a = *(const float4*)(arow + (size_t)r * L + jt + c);
      At[r][c] = a.x; At[r][c + 1] = a.y; At[r][c + 2] = a.z; At[r][c + 3] = a.w;
      float4 vv = *(const float4*)(vb + (size_t)(jt + r) * D + c);
      Vt[r][c] = vv.x; Vt[r][c + 1] = vv.y; Vt[r][c + 2] = vv.z; Vt[r][c + 3] = vv.w;
    }
    __syncthreads();
#pragma unroll 8
    for (int jj = 0; jj < 64; ++jj) {
      float a0 = At[ti][jj], a1 = At[ti + 1][jj], a2 = At[ti + 2][jj], a3 = At[ti + 3][jj];
      float b0 = Vt[jj][td], b1 = Vt[jj][td + 1], b2 = Vt[jj][td + 2], b3 = Vt[jj][td + 3];
      acc[0][0] += a0 * b0; acc[0][1] += a0 * b1; acc[0][2] += a0 * b2; acc[0][3] += a0 * b3;
      acc[1][0] += a1 * b0; acc[1][1] += a1 * b1; acc[1][2] += a1 * b2; acc[1][3] += a1 * b3;
      acc[2][0] += a2 * b0; acc[2][1] += a2 * b1; acc[2][2] += a2 * b2; acc[2][3] += a2 * b3;
      acc[3][0] += a3 * b0; acc[3][1] += a3 * b1; acc[3][2] += a3 * b2; acc[3][3] += a3 * b3;
    }
  }
  float* orow = out + ((size_t)bh * L + it * 64) * D;
#pragma unroll
  for (int m = 0; m < 4; ++m)
    *(float4*)(orow + (size_t)(ti + m) * D + td) =
        make_float4(acc[m][0], acc[m][1], acc[m][2], acc[m][3]);
}

// ---------------------------------------------------------------------------
// K3b: per (b,i): out[b,h,i,d] += sum_j attn[b,h,i,j] * adj_v[b,i,j,d]
// grid (B*L), block 256. Streams adj_v through LDS chunks.
// ---------------------------------------------------------------------------
__global__ __launch_bounds__(256) void k3b_rel_out(const float* __restrict__ attn,
                                                   const float* __restrict__ adj_v,
                                                   float* __restrict__ out) {
  const int b = blockIdx.x >> 9, i = blockIdx.x & (L - 1);
  __shared__ float at[NH][L];    // 16 KB
  __shared__ float av[64][65];   // 16.6 KB, padded
  const int t = threadIdx.x;
  // load attn rows for this (b,i): flat, coalesced, conflict-free
  float* atf = &at[0][0];
  for (int n = t; n < NH * L; n += 256) {
    int h = n >> 9, jj = n & (L - 1);
    atf[n] = attn[(((size_t)b * NH + h) * L + i) * L + jj];
  }
  const float* avb = adj_v + ((size_t)b * L + i) * (size_t)L * D;
  const int d = t & 63, h0 = t >> 6;         // heads h0 and h0+4
  float acc0 = 0.f, acc1 = 0.f;
  for (int jt = 0; jt < L; jt += 64) {
    __syncthreads();
#pragma unroll
    for (int n = 0; n < 4; ++n) {
      int idx = t + (n << 8);
      int r = idx >> 4, c = (idx & 15) << 2;
      float4 a = *(const float4*)(avb + (size_t)(jt + r) * D + c);
      av[r][c] = a.x; av[r][c + 1] = a.y; av[r][c + 2] = a.z; av[r][c + 3] = a.w;
    }
    __syncthreads();
#pragma unroll
    for (int jj = 0; jj < 64; jj += 4) {
      float4 a0 = *(const float4*)&at[h0][jt + jj];        // broadcast
      float4 a1 = *(const float4*)&at[h0 + 4][jt + jj];    // broadcast
      float v0 = av[jj][d], v1 = av[jj + 1][d], v2 = av[jj + 2][d], v3 = av[jj + 3][d];
      acc0 += a0.x * v0 + a0.y * v1 + a0.z * v2 + a0.w * v3;
      acc1 += a1.x * v0 + a1.y * v1 + a1.z * v2 + a1.w * v3;
    }
  }
  const size_t o0 = (((size_t)b * NH + h0) * L + i) * D + d;
  out[o0] += acc0;                               // K3a wrote these; RMW is
  out[o0 + (size_t)4 * L * D] += acc1;           // per-thread exclusive
}

// ---------------------------------------------------------------------------
extern "C" void kernel_launch(void* const* d_in, const int* in_sizes, int n_in,
                              void* d_out, int out_size, void* d_ws, size_t ws_size,
                              hipStream_t stream) {
  const float* q     = (const float*)d_in[0];
  const float* k     = (const float*)d_in[1];
  const float* v     = (const float*)d_in[2];
  const float* adj_k = (const float*)d_in[3];
  const float* adj_v = (const float*)d_in[4];
  const int*   mask  = (const int*)d_in[5];
  float* out  = (float*)d_out;
  float* attn = out + (size_t)B * NH * L * D;   // second output region

  dim3 g1(B * NH, L / 64, L / 64);
  k1_qk<<<g1, 256, 0, stream>>>(q, k, attn);
  k2_rel_softmax<<<B * L, 256, 0, stream>>>(q, adj_k, mask, attn);
  dim3 g3(B * NH, L / 64);
  k3a_av<<<g3, 256, 0, stream>>>(attn, v, out);
  k3b_rel_out<<<B * L, 256, 0, stream>>>(attn, adj_v, out);
}